// Round 3
// baseline (1570.884 us; speedup 1.0000x reference)
//
#include <hip/hip_runtime.h>
#include <cstdio>

typedef unsigned short u16;
typedef __bf16 bf16x8 __attribute__((ext_vector_type(8)));
typedef float  floatx4 __attribute__((ext_vector_type(4)));

// ---------- scalar helpers ----------
__device__ __forceinline__ float bf2f(u16 u) {
  union { unsigned int i; float f; } v; v.i = ((unsigned int)u) << 16; return v.f;
}
__device__ __forceinline__ u16 f2bf(float f) {
  union { float f; unsigned int i; } v; v.f = f;
  unsigned int x = v.i;
  return (u16)((x + 0x7fffu + ((x >> 16) & 1u)) >> 16);   // RNE
}
__device__ __forceinline__ float sigmoidf_(float x) { return 1.f / (1.f + __expf(-x)); }
__device__ __forceinline__ float tanhf_(float x) {
  float ax = fabsf(x);
  float e = __expf(-2.f * ax);
  return copysignf((1.f - e) / (1.f + e), x);
}

// LDS swizzle: 16B chunks, chunk' = chunk ^ (row&15). 128 u16 per row, no pad.
__device__ __forceinline__ int swz(int row, int chunk) {
  return row * 128 + ((chunk ^ (row & 15)) << 3);
}

// ---------- fused-staging MFMA tile: C(128x128) = A(128x256) @ B(256x128) ----------
// B transposed: BT[n][k]. MODE 0 (parents): K = [ x=emb[sen[o0+m]] | h_sum ratio children ]
//   (ratio==0 => leaf => h_sum=0). MODE 1 (children): K = [ h_child[m] | x_parent ].
// x gathered from fp32 emb with on-the-fly bf16 convert.
__device__ __forceinline__ void mfma_tile(
    const int* __restrict__ sen, const float* __restrict__ emb,
    const u16* __restrict__ h_prev, const u16* __restrict__ BT,
    long o0, int ratio, int lr, int mode, floatx4 acc[4][4])
{
  __shared__ __align__(16) u16 ldsA[128 * 128];   // 32 KB
  __shared__ __align__(16) u16 ldsB[128 * 128];   // 32 KB (total exactly 64 KB)
  const int tid  = threadIdx.x;
  const long m0  = (long)blockIdx.x * 128;
  const int n0   = blockIdx.y * 128;
  const int r    = tid >> 1;            // staging row 0..127
  const int cb8  = (tid & 1) * 8;       // chunk base (16B chunks)
  const int cbase= cb8 * 8;             // element base (0 or 64)
  const int lane = tid & 63, wave = tid >> 6;
  const int wr   = (wave >> 1) * 64, wc = (wave & 1) * 64;
  const int l16  = lane & 15, quad = lane >> 4;

  for (int kc = 0; kc < 2; kc++) {
    __syncthreads();
    // ---- stage B chunk ----
    {
      const u16* src = BT + (long)(n0 + r) * 256 + kc * 128 + cbase;
#pragma unroll
      for (int i = 0; i < 8; i++)
        *reinterpret_cast<uint4*>(&ldsB[swz(r, cb8 + i)]) =
            *reinterpret_cast<const uint4*>(src + i * 8);
    }
    // ---- stage A chunk ----
    const bool x_chunk = (mode == 0) ? (kc == 0) : (kc == 1);
    if (x_chunk) {
      const long node = (mode == 0) ? (o0 + m0 + r) : (o0 + ((m0 + r) >> lr));
      const float* src = emb + (long)sen[node] * 128 + cbase;
#pragma unroll
      for (int i = 0; i < 8; i++) {
        float4 v0 = *reinterpret_cast<const float4*>(src + i * 8);
        float4 v1 = *reinterpret_cast<const float4*>(src + i * 8 + 4);
        u16 ov[8] = { f2bf(v0.x), f2bf(v0.y), f2bf(v0.z), f2bf(v0.w),
                      f2bf(v1.x), f2bf(v1.y), f2bf(v1.z), f2bf(v1.w) };
        *reinterpret_cast<uint4*>(&ldsA[swz(r, cb8 + i)]) =
            *reinterpret_cast<const uint4*>(ov);
      }
    } else if (mode == 1) {            // children h rows
      const u16* src = h_prev + (m0 + r) * 128 + cbase;
#pragma unroll
      for (int i = 0; i < 8; i++)
        *reinterpret_cast<uint4*>(&ldsA[swz(r, cb8 + i)]) =
            *reinterpret_cast<const uint4*>(src + i * 8);
    } else if (ratio == 0) {           // leaf h_sum = 0
      const uint4 z = make_uint4(0u, 0u, 0u, 0u);
#pragma unroll
      for (int i = 0; i < 8; i++)
        *reinterpret_cast<uint4*>(&ldsA[swz(r, cb8 + i)]) = z;
    } else {                           // parent h_sum over ratio children
      const u16* hb = h_prev + (m0 + r) * (long)ratio * 128 + cbase;
#pragma unroll
      for (int i = 0; i < 8; i++) {
        float s[8] = {0.f, 0.f, 0.f, 0.f, 0.f, 0.f, 0.f, 0.f};
        for (int cr = 0; cr < ratio; cr++) {
          uint4 v = *reinterpret_cast<const uint4*>(hb + cr * 128 + i * 8);
          const u16* p = reinterpret_cast<const u16*>(&v);
#pragma unroll
          for (int e = 0; e < 8; e++) s[e] += bf2f(p[e]);
        }
        u16 ov[8];
#pragma unroll
        for (int e = 0; e < 8; e++) ov[e] = f2bf(s[e]);
        *reinterpret_cast<uint4*>(&ldsA[swz(r, cb8 + i)]) =
            *reinterpret_cast<const uint4*>(ov);
      }
    }
    __syncthreads();
    // ---- MFMA over this K-chunk ----
#pragma unroll
    for (int ks = 0; ks < 4; ks++) {
      bf16x8 af[4], bfv[4];
#pragma unroll
      for (int t = 0; t < 4; t++) {
        af[t]  = *reinterpret_cast<const bf16x8*>(&ldsA[swz(wr + t * 16 + l16, ks * 4 + quad)]);
        bfv[t] = *reinterpret_cast<const bf16x8*>(&ldsB[swz(wc + t * 16 + l16, ks * 4 + quad)]);
      }
#pragma unroll
      for (int i = 0; i < 4; i++)
#pragma unroll
        for (int j = 0; j < 4; j++)
          acc[i][j] = __builtin_amdgcn_mfma_f32_16x16x32_bf16(af[i], bfv[j], acc[i][j], 0, 0, 0);
    }
  }
}

#define ACC_INIT(acc) \
  _Pragma("unroll") for (int i = 0; i < 4; i++) \
  _Pragma("unroll") for (int j = 0; j < 4; j++) acc[i][j] = (floatx4){0.f, 0.f, 0.f, 0.f};

// ---------- k_iu: interleaved i/u gates; epilogue writes c = sig(i)*tanh(u) + fc_sum ----------
__global__ __launch_bounds__(256, 2) void k_iu(
    const int* __restrict__ sen, const float* __restrict__ emb,
    const u16* __restrict__ h_prev, const u16* __restrict__ BT,
    const u16* __restrict__ fcsum, u16* __restrict__ c_out,
    const float* __restrict__ b_ix, const float* __restrict__ b_ih,
    const float* __restrict__ b_ux, const float* __restrict__ b_uh,
    long o0, int ratio, int has_fc)
{
  floatx4 acc[4][4];
  ACC_INIT(acc)
  mfma_tile(sen, emb, h_prev, BT, o0, ratio, 0, 0, acc);

  const int tid = threadIdx.x, lane = tid & 63, wave = tid >> 6;
  const long m0 = (long)blockIdx.x * 128;
  const int n0 = blockIdx.y * 128;
  const int wr = (wave >> 1) * 64, wc = (wave & 1) * 64, l16 = lane & 15, quad = lane >> 4;
  const int g = l16 & 1;   // 0 = i (sigmoid), 1 = u (tanh)
#pragma unroll
  for (int i = 0; i < 4; i++) {
#pragma unroll
    for (int j = 0; j < 4; j++) {
      const int np = n0 + wc + j * 16 + l16;
      const int jcol = np >> 1;
      const float bb = g ? (b_ux[jcol] + b_uh[jcol]) : (b_ix[jcol] + b_ih[jcol]);
#pragma unroll
      for (int r2 = 0; r2 < 4; r2++) {
        const long gr = m0 + wr + i * 16 + quad * 4 + r2;   // C/D: row=quad*4+reg, col=lane&15
        const float pre = acc[i][j][r2] + bb;
        const float act = g ? tanhf_(pre) : sigmoidf_(pre);
        const float part = __shfl_xor(act, 1);
        if (!g) {
          float c = act * part;
          if (has_fc) c += bf2f(fcsum[gr * 128 + jcol]);
          c_out[gr * 128 + jcol] = f2bf(c);
        }
      }
    }
  }
}

// ---------- k_o: o-gate; epilogue h = sigmoid(o)*tanh(c) ----------
__global__ __launch_bounds__(256, 2) void k_o(
    const int* __restrict__ sen, const float* __restrict__ emb,
    const u16* __restrict__ h_prev, const u16* __restrict__ BT,
    const u16* __restrict__ c_cur, u16* __restrict__ h_out,
    const float* __restrict__ b_ox, const float* __restrict__ b_oh,
    long o0, int ratio)
{
  floatx4 acc[4][4];
  ACC_INIT(acc)
  mfma_tile(sen, emb, h_prev, BT, o0, ratio, 0, 0, acc);

  const int tid = threadIdx.x, lane = tid & 63, wave = tid >> 6;
  const long m0 = (long)blockIdx.x * 128;
  const int wr = (wave >> 1) * 64, wc = (wave & 1) * 64, l16 = lane & 15, quad = lane >> 4;
#pragma unroll
  for (int i = 0; i < 4; i++) {
#pragma unroll
    for (int j = 0; j < 4; j++) {
      const int jc = wc + j * 16 + l16;
      const float bb = b_ox[jc] + b_oh[jc];
#pragma unroll
      for (int r2 = 0; r2 < 4; r2++) {
        const long gr = m0 + wr + i * 16 + quad * 4 + r2;
        const float o = sigmoidf_(acc[i][j][r2] + bb);
        const float c = bf2f(c_cur[gr * 128 + jc]);
        h_out[gr * 128 + jc] = f2bf(o * tanhf_(c));
      }
    }
  }
}

// ---------- k_fc: f-gate over children; epilogue group-sums f*c into fcsum[parent] ----------
__global__ __launch_bounds__(256, 2) void k_fc(
    const int* __restrict__ sen, const float* __restrict__ emb,
    const u16* __restrict__ h_prev, const u16* __restrict__ BT,
    const u16* __restrict__ c_prev, u16* __restrict__ fcsum,
    const float* __restrict__ b_fh, const float* __restrict__ b_fx,
    long o0, int lr)
{
  floatx4 acc[4][4];
  ACC_INIT(acc)
  mfma_tile(sen, emb, h_prev, BT, o0, 0, lr, 1, acc);

  const int tid = threadIdx.x, lane = tid & 63, wave = tid >> 6;
  const long m0 = (long)blockIdx.x * 128;
  const int wr = (wave >> 1) * 64, wc = (wave & 1) * 64, l16 = lane & 15, quad = lane >> 4;
#pragma unroll
  for (int i = 0; i < 4; i++) {
    const long base = m0 + wr + i * 16 + quad * 4;   // multiple of 4
#pragma unroll
    for (int j = 0; j < 4; j++) {
      const int jc = wc + j * 16 + l16;
      const float bb = b_fh[jc] + b_fx[jc];
      float fcv[4];
#pragma unroll
      for (int r2 = 0; r2 < 4; r2++) {
        const float f = sigmoidf_(acc[i][j][r2] + bb);
        fcv[r2] = f * bf2f(c_prev[(base + r2) * 128 + jc]);
      }
      if (lr == 2) {
        fcsum[(base >> 2) * 128 + jc] = f2bf(fcv[0] + fcv[1] + fcv[2] + fcv[3]);
      } else if (lr == 1) {
        fcsum[(base >> 1) * 128 + jc]       = f2bf(fcv[0] + fcv[1]);
        fcsum[((base >> 1) + 1) * 128 + jc] = f2bf(fcv[2] + fcv[3]);
      } else {
#pragma unroll
        for (int r2 = 0; r2 < 4; r2++)
          fcsum[(base + r2) * 128 + jc] = f2bf(fcv[r2]);
      }
    }
  }
}

// ---------- weight prep ----------
__global__ void build_wiuT(const float* __restrict__ Wix, const float* __restrict__ Wih,
                           const float* __restrict__ Wux, const float* __restrict__ Wuh,
                           u16* __restrict__ BT)
{
  int idx = blockIdx.x * 256 + threadIdx.x;   // 256*256
  int np = idx >> 8, k = idx & 255;
  int g = np & 1, j = np >> 1;
  float v = (k < 128) ? (g ? Wux[k * 128 + j] : Wix[k * 128 + j])
                      : (g ? Wuh[(k - 128) * 128 + j] : Wih[(k - 128) * 128 + j]);
  BT[idx] = f2bf(v);
}

__global__ void build_woT(const float* __restrict__ Wox, const float* __restrict__ Woh,
                          u16* __restrict__ BT)
{
  int idx = blockIdx.x * 256 + threadIdx.x;   // 128*256
  int n = idx >> 8, k = idx & 255;
  float v = (k < 128) ? Wox[k * 128 + n] : Woh[(k - 128) * 128 + n];
  BT[idx] = f2bf(v);
}

__global__ void build_wfT(const float* __restrict__ Wfh, const float* __restrict__ Wfx,
                          u16* __restrict__ BT)
{
  int idx = blockIdx.x * 256 + threadIdx.x;   // 128*256
  int n = idx >> 8, k = idx & 255;
  float v = (k < 128) ? Wfh[k * 128 + n] : Wfx[(k - 128) * 128 + n];
  BT[idx] = f2bf(v);
}

// ---------- output projection (4096 x 4, tiny) ----------
__global__ void out_proj(const u16* __restrict__ h_root, const float* __restrict__ W_out,
                         const float* __restrict__ b_out, float* __restrict__ out)
{
  int idx = blockIdx.x * 256 + threadIdx.x;   // 4096*4
  int n = idx >> 2, cls = idx & 3;
  float s = b_out[cls];
  for (int k = 0; k < 128; k++)
    s += bf2f(h_root[(long)n * 128 + k]) * W_out[k * 4 + cls];
  out[idx] = s;
}

extern "C" void kernel_launch(void* const* d_in, const int* in_sizes, int n_in,
                              void* d_out, int out_size, void* d_ws, size_t ws_size,
                              hipStream_t stream)
{
  const int*   sen  = (const int*)d_in[0];
  const float* emb  = (const float*)d_in[1];
  const float* W_ix = (const float*)d_in[2];  const float* b_ix = (const float*)d_in[3];
  const float* W_ih = (const float*)d_in[4];  const float* b_ih = (const float*)d_in[5];
  const float* W_fx = (const float*)d_in[6];  const float* b_fx = (const float*)d_in[7];
  const float* W_fh = (const float*)d_in[8];  const float* b_fh = (const float*)d_in[9];
  const float* W_ox = (const float*)d_in[10]; const float* b_ox = (const float*)d_in[11];
  const float* W_oh = (const float*)d_in[12]; const float* b_oh = (const float*)d_in[13];
  const float* W_ux = (const float*)d_in[14]; const float* b_ux = (const float*)d_in[15];
  const float* W_uh = (const float*)d_in[16]; const float* b_uh = (const float*)d_in[17];
  const float* W_out= (const float*)d_in[18]; const float* b_out= (const float*)d_in[19];
  float* out = (float*)d_out;

  // ---- workspace layout: 3 rotating 67.1 MB buffers + small weights (~202 MB) ----
  const size_t SLOT = (size_t)262144 * 128 * 2;
  const size_t need = 3 * SLOT + ((size_t)256 * 256 + 2 * 128 * 256) * 2 + 4096;
  fprintf(stderr, "[tree_lstm] ws_size=%zu need=%zu\n", ws_size, need);
  if (ws_size < need) {
    fprintf(stderr, "[tree_lstm] INSUFFICIENT WORKSPACE — skipping launch\n");
    return;
  }
  char* ws = (char*)d_ws;
  size_t off = 0;
  auto take = [&](size_t bytes) { char* p = ws + off; off += (bytes + 255) & ~(size_t)255; return p; };
  u16* X  = (u16*)take(SLOT);   // h_prev / h_cur (rotates with Y)
  u16* Bc = (u16*)take(SLOT);   // c (prev then cur — sequenced by kernel order)
  u16* Y  = (u16*)take(SLOT);   // fcsum then h_cur (rotates with X)
  u16* WiuT = (u16*)take((size_t)256 * 256 * 2);
  u16* WoT  = (u16*)take((size_t)128 * 256 * 2);
  u16* WfT  = (u16*)take((size_t)128 * 256 * 2);

  // ---- prep ----
  build_wiuT<<<256, 256, 0, stream>>>(W_ix, W_ih, W_ux, W_uh, WiuT);
  build_woT<<<128, 256, 0, stream>>>(W_ox, W_oh, WoT);
  build_wfT<<<128, 256, 0, stream>>>(W_fh, W_fx, WfT);

  const long LOFF[6] = {0, 4096, 20480, 86016, 217088, 479232};
  const int  LSZ[6]  = {4096, 16384, 65536, 131072, 262144, 262144};
  const int  LLR[5]  = {2, 2, 1, 1, 0};   // log2(children per node), L=0..4

  // ---- leaf level L=5: c -> Bc, h -> X ----
  {
    long o0 = LOFF[5]; int nL = LSZ[5];
    k_iu<<<dim3(nL / 128, 2), 256, 0, stream>>>(sen, emb, X, WiuT,
        Y, Bc, b_ix, b_ih, b_ux, b_uh, o0, 0, 0);
    k_o<<<dim3(nL / 128, 1), 256, 0, stream>>>(sen, emb, X, WoT,
        Bc, X, b_ox, b_oh, o0, 0);
  }
  // ---- levels 4..0: h_prev=X, c_prev=Bc; fcsum->Y; c_cur->Bc; h_cur->Y; swap(X,Y) ----
  for (int L = 4; L >= 0; L--) {
    const long o0 = LOFF[L];
    const int nL = LSZ[L], nC = LSZ[L + 1];
    const int lr = LLR[L], ratio = 1 << lr;
    k_fc<<<dim3(nC / 128, 1), 256, 0, stream>>>(sen, emb, X, WfT,
        Bc, Y, b_fh, b_fx, o0, lr);
    k_iu<<<dim3(nL / 128, 2), 256, 0, stream>>>(sen, emb, X, WiuT,
        Y, Bc, b_ix, b_ih, b_ux, b_uh, o0, ratio, 1);
    k_o<<<dim3(nL / 128, 1), 256, 0, stream>>>(sen, emb, X, WoT,
        Bc, Y, b_ox, b_oh, o0, ratio);
    u16* t = X; X = Y; Y = t;
  }

  out_proj<<<64, 256, 0, stream>>>(X, W_out, b_out, out);
}

// Round 4
// 1096.474 us; speedup vs baseline: 1.4327x; 1.4327x over previous
//
#include <hip/hip_runtime.h>
#include <cstdio>

typedef unsigned short u16;
typedef __bf16 bf16x8 __attribute__((ext_vector_type(8)));
typedef float  floatx4 __attribute__((ext_vector_type(4)));

// ---------- scalar helpers ----------
__device__ __forceinline__ float bf2f(u16 u) {
  union { unsigned int i; float f; } v; v.i = ((unsigned int)u) << 16; return v.f;
}
__device__ __forceinline__ u16 f2bf(float f) {
  union { float f; unsigned int i; } v; v.f = f;
  unsigned int x = v.i;
  return (u16)((x + 0x7fffu + ((x >> 16) & 1u)) >> 16);   // RNE
}
__device__ __forceinline__ float sigmoidf_(float x) { return 1.f / (1.f + __expf(-x)); }
__device__ __forceinline__ float tanhf_(float x) {
  float ax = fabsf(x);
  float e = __expf(-2.f * ax);
  return copysignf((1.f - e) / (1.f + e), x);
}

// LDS swizzle: 16B chunks, chunk' = chunk ^ (row&15) (XOR within 16-chunk halves).
// rowlen16 = chunks per row (16 for K=128, 32 for K=256).
__device__ __forceinline__ int swzk(int row, int c16, int rowlen16) {
  return row * (rowlen16 * 8) + ((c16 ^ (row & 15)) << 3);
}

// ---------- one MFMA pass: 64x64 per wave over K = KC*128, A from LDS, B from global ----------
// BT rows are 256 k-elements wide always (KC=1 reads only first 128 — h-part is zero at leaf).
template<int KC>
__device__ __forceinline__ void mm_pass(const u16* ldsA, const u16* __restrict__ BT,
                                        int nb, int wr, int l16, int quad,
                                        floatx4 acc[4][4])
{
#pragma unroll
  for (int i = 0; i < 4; i++)
#pragma unroll
    for (int j = 0; j < 4; j++) acc[i][j] = (floatx4){0.f, 0.f, 0.f, 0.f};
#pragma unroll
  for (int kc = 0; kc < KC; kc++)
#pragma unroll
    for (int ks = 0; ks < 4; ks++) {
      bf16x8 a[4], b[4];
#pragma unroll
      for (int j = 0; j < 4; j++)
        b[j] = *reinterpret_cast<const bf16x8*>(
            BT + (size_t)(nb + j * 16 + l16) * 256 + kc * 128 + ks * 32 + quad * 8);
#pragma unroll
      for (int i = 0; i < 4; i++)
        a[i] = *reinterpret_cast<const bf16x8*>(
            &ldsA[swzk(wr + i * 16 + l16, kc * 16 + ks * 4 + quad, KC * 16)]);
#pragma unroll
      for (int i = 0; i < 4; i++)
#pragma unroll
        for (int j = 0; j < 4; j++)
          acc[i][j] = __builtin_amdgcn_mfma_f32_16x16x32_bf16(a[i], b[j], acc[i][j], 0, 0, 0);
    }
}

// ---------- k_cell: fused i/u/o for one level's parents ----------
// A row m (staged once, full K): [ x = emb[sen[o0+m]] | h_sum over ratio children ]
// Pass structure per wave (wc): iu sub-passes s=0,1 at B_iu rows 2wc+64s (i/u 16-col-group
// interleaved -> same lane owns i and u of a column), then o-pass at B_o rows wc.
// Epilogue: c = sig(i)*tanh(u) + fcsum ; h = sig(o)*tanh(c). fcsum may alias h_out (per-lane
// read-before-write on identical (row,col) ownership).
template<int KC>
__global__ __launch_bounds__(256, 2) void k_cell(
    const int* __restrict__ sen, const float* __restrict__ emb,
    const u16* __restrict__ h_prev, const u16* __restrict__ Biu,
    const u16* __restrict__ Bo, const u16* fcsum,
    u16* __restrict__ c_out, u16* h_out,
    const float* __restrict__ b_ix, const float* __restrict__ b_ih,
    const float* __restrict__ b_ux, const float* __restrict__ b_uh,
    const float* __restrict__ b_ox, const float* __restrict__ b_oh,
    long o0, int ratio, int has_fc)
{
  __shared__ __align__(16) u16 ldsA[128 * KC * 128];   // 32 KB (KC=1) / 64 KB (KC=2)
  const int tid = threadIdx.x;
  const long m0 = (long)blockIdx.x * 128;
  const int r = tid >> 1;

  // ---- stage A (full K), one barrier ----
  {
    const float* xsrc = emb + (size_t)sen[o0 + m0 + r] * 128;
#pragma unroll
    for (int i = 0; i < KC * 8; i++) {
      const int c16 = (tid & 1) + 2 * i;
      u16* dst = &ldsA[swzk(r, c16, KC * 16)];
      if (c16 < 16) {                       // x part
        const float* s = xsrc + c16 * 8;
        float4 v0 = *reinterpret_cast<const float4*>(s);
        float4 v1 = *reinterpret_cast<const float4*>(s + 4);
        u16 ov[8] = { f2bf(v0.x), f2bf(v0.y), f2bf(v0.z), f2bf(v0.w),
                      f2bf(v1.x), f2bf(v1.y), f2bf(v1.z), f2bf(v1.w) };
        *reinterpret_cast<uint4*>(dst) = *reinterpret_cast<const uint4*>(ov);
      } else if (ratio == 0) {              // leaf: h_sum = 0
        *reinterpret_cast<uint4*>(dst) = make_uint4(0u, 0u, 0u, 0u);
      } else {                              // h_sum over children
        const u16* hb = h_prev + (m0 + r) * (long)ratio * 128 + (c16 - 16) * 8;
        float s8[8] = {0.f, 0.f, 0.f, 0.f, 0.f, 0.f, 0.f, 0.f};
        for (int cr = 0; cr < ratio; cr++) {
          uint4 v = *reinterpret_cast<const uint4*>(hb + cr * 128);
          const u16* p = reinterpret_cast<const u16*>(&v);
#pragma unroll
          for (int e = 0; e < 8; e++) s8[e] += bf2f(p[e]);
        }
        u16 ov[8];
#pragma unroll
        for (int e = 0; e < 8; e++) ov[e] = f2bf(s8[e]);
        *reinterpret_cast<uint4*>(dst) = *reinterpret_cast<const uint4*>(ov);
      }
    }
  }
  __syncthreads();

  const int lane = tid & 63, wave = tid >> 6;
  const int wr = (wave >> 1) * 64, wc = (wave & 1) * 64;
  const int l16 = lane & 15, quad = lane >> 4;

  floatx4 acc[4][4];
  float tch[4][4][4];   // tanh(c): [i][col-group gl][r2]

  // ---- i/u sub-passes ----
#pragma unroll
  for (int s = 0; s < 2; s++) {
    mm_pass<KC>(ldsA, Biu, 2 * wc + 64 * s, wr, l16, quad, acc);
#pragma unroll
    for (int pp = 0; pp < 2; pp++) {
      const int gl = s * 2 + pp;
      const int col = wc + gl * 16 + l16;
      const float bi = b_ix[col] + b_ih[col];
      const float bu = b_ux[col] + b_uh[col];
#pragma unroll
      for (int i = 0; i < 4; i++) {
#pragma unroll
        for (int r2 = 0; r2 < 4; r2++) {
          const long row = m0 + wr + i * 16 + quad * 4 + r2;
          float cv = sigmoidf_(acc[i][2 * pp][r2] + bi) * tanhf_(acc[i][2 * pp + 1][r2] + bu);
          if (has_fc) cv += bf2f(fcsum[row * 128 + col]);
          c_out[row * 128 + col] = f2bf(cv);
          tch[i][gl][r2] = tanhf_(cv);
        }
      }
    }
  }
  // ---- o pass ----
  mm_pass<KC>(ldsA, Bo, wc, wr, l16, quad, acc);
#pragma unroll
  for (int j = 0; j < 4; j++) {
    const int col = wc + j * 16 + l16;
    const float bo = b_ox[col] + b_oh[col];
#pragma unroll
    for (int i = 0; i < 4; i++)
#pragma unroll
      for (int r2 = 0; r2 < 4; r2++) {
        const long row = m0 + wr + i * 16 + quad * 4 + r2;
        const float h = sigmoidf_(acc[i][j][r2] + bo) * tch[i][j][r2];
        h_out[row * 128 + col] = f2bf(h);
      }
  }
}

// ---------- k_fc: f-gate over children; epilogue group-sums f*c into fcsum[parent] ----------
// A row m: [ h_child[m] | x_parent = emb[sen[o0 + (m>>lr)]] ]
__global__ __launch_bounds__(256, 2) void k_fc(
    const int* __restrict__ sen, const float* __restrict__ emb,
    const u16* __restrict__ h_prev, const u16* __restrict__ Bf,
    const u16* __restrict__ c_prev, u16* __restrict__ fcsum,
    const float* __restrict__ b_fh, const float* __restrict__ b_fx,
    long o0, int lr)
{
  __shared__ __align__(16) u16 ldsA[128 * 256];   // 64 KB
  const int tid = threadIdx.x;
  const long m0 = (long)blockIdx.x * 128;
  const int r = tid >> 1;

  {
    const float* xsrc = emb + (size_t)sen[o0 + ((m0 + r) >> lr)] * 128;
    const u16* hsrc = h_prev + (m0 + r) * 128;
#pragma unroll
    for (int i = 0; i < 16; i++) {
      const int c16 = (tid & 1) + 2 * i;
      u16* dst = &ldsA[swzk(r, c16, 32)];
      if (c16 < 16) {
        *reinterpret_cast<uint4*>(dst) = *reinterpret_cast<const uint4*>(hsrc + c16 * 8);
      } else {
        const float* s = xsrc + (c16 - 16) * 8;
        float4 v0 = *reinterpret_cast<const float4*>(s);
        float4 v1 = *reinterpret_cast<const float4*>(s + 4);
        u16 ov[8] = { f2bf(v0.x), f2bf(v0.y), f2bf(v0.z), f2bf(v0.w),
                      f2bf(v1.x), f2bf(v1.y), f2bf(v1.z), f2bf(v1.w) };
        *reinterpret_cast<uint4*>(dst) = *reinterpret_cast<const uint4*>(ov);
      }
    }
  }
  __syncthreads();

  const int lane = tid & 63, wave = tid >> 6;
  const int wr = (wave >> 1) * 64, wc = (wave & 1) * 64;
  const int l16 = lane & 15, quad = lane >> 4;

  floatx4 acc[4][4];
  mm_pass<2>(ldsA, Bf, wc, wr, l16, quad, acc);

#pragma unroll
  for (int i = 0; i < 4; i++) {
    const long base = m0 + wr + i * 16 + quad * 4;   // multiple of 4
#pragma unroll
    for (int j = 0; j < 4; j++) {
      const int jc = wc + j * 16 + l16;
      const float bb = b_fh[jc] + b_fx[jc];
      float fcv[4];
#pragma unroll
      for (int r2 = 0; r2 < 4; r2++) {
        const float f = sigmoidf_(acc[i][j][r2] + bb);
        fcv[r2] = f * bf2f(c_prev[(base + r2) * 128 + jc]);
      }
      if (lr == 2) {
        fcsum[(base >> 2) * 128 + jc] = f2bf(fcv[0] + fcv[1] + fcv[2] + fcv[3]);
      } else if (lr == 1) {
        fcsum[(base >> 1) * 128 + jc]       = f2bf(fcv[0] + fcv[1]);
        fcsum[((base >> 1) + 1) * 128 + jc] = f2bf(fcv[2] + fcv[3]);
      } else {
#pragma unroll
        for (int r2 = 0; r2 < 4; r2++)
          fcsum[(base + r2) * 128 + jc] = f2bf(fcv[r2]);
      }
    }
  }
}

// ---------- weight prep ----------
// B_iu [256 n'][256 k]: n' -> (wave-half, sub s, tile j, lane l): gate = j&1 (0=i,1=u),
// col = (n'>>7)*64 + (s*2 + (j>>1))*16 + l. k<128 -> W_gx[k][col], else W_gh[k-128][col].
__global__ void build_biu(const float* __restrict__ Wix, const float* __restrict__ Wih,
                          const float* __restrict__ Wux, const float* __restrict__ Wuh,
                          u16* __restrict__ BT)
{
  int idx = blockIdx.x * 256 + threadIdx.x;   // 256*256
  int np = idx >> 8, k = idx & 255;
  int wcb = (np >> 7) * 64;
  int rem = np & 127;
  int s = rem >> 6;
  int j = (rem >> 4) & 3;
  int l = np & 15;
  int gate = j & 1;
  int col = wcb + (s * 2 + (j >> 1)) * 16 + l;
  float v = (k < 128) ? (gate ? Wux[k * 128 + col] : Wix[k * 128 + col])
                      : (gate ? Wuh[(k - 128) * 128 + col] : Wih[(k - 128) * 128 + col]);
  BT[idx] = f2bf(v);
}

__global__ void build_bo(const float* __restrict__ Wox, const float* __restrict__ Woh,
                         u16* __restrict__ BT)
{
  int idx = blockIdx.x * 256 + threadIdx.x;   // 128*256
  int n = idx >> 8, k = idx & 255;
  float v = (k < 128) ? Wox[k * 128 + n] : Woh[(k - 128) * 128 + n];
  BT[idx] = f2bf(v);
}

__global__ void build_bf(const float* __restrict__ Wfh, const float* __restrict__ Wfx,
                         u16* __restrict__ BT)
{
  int idx = blockIdx.x * 256 + threadIdx.x;   // 128*256
  int n = idx >> 8, k = idx & 255;
  float v = (k < 128) ? Wfh[k * 128 + n] : Wfx[(k - 128) * 128 + n];
  BT[idx] = f2bf(v);
}

// ---------- output projection (4096 x 4, tiny) ----------
__global__ void out_proj(const u16* __restrict__ h_root, const float* __restrict__ W_out,
                         const float* __restrict__ b_out, float* __restrict__ out)
{
  int idx = blockIdx.x * 256 + threadIdx.x;   // 4096*4
  int n = idx >> 2, cls = idx & 3;
  float s = b_out[cls];
  for (int k = 0; k < 128; k++)
    s += bf2f(h_root[(long)n * 128 + k]) * W_out[k * 4 + cls];
  out[idx] = s;
}

extern "C" void kernel_launch(void* const* d_in, const int* in_sizes, int n_in,
                              void* d_out, int out_size, void* d_ws, size_t ws_size,
                              hipStream_t stream)
{
  const int*   sen  = (const int*)d_in[0];
  const float* emb  = (const float*)d_in[1];
  const float* W_ix = (const float*)d_in[2];  const float* b_ix = (const float*)d_in[3];
  const float* W_ih = (const float*)d_in[4];  const float* b_ih = (const float*)d_in[5];
  const float* W_fx = (const float*)d_in[6];  const float* b_fx = (const float*)d_in[7];
  const float* W_fh = (const float*)d_in[8];  const float* b_fh = (const float*)d_in[9];
  const float* W_ox = (const float*)d_in[10]; const float* b_ox = (const float*)d_in[11];
  const float* W_oh = (const float*)d_in[12]; const float* b_oh = (const float*)d_in[13];
  const float* W_ux = (const float*)d_in[14]; const float* b_ux = (const float*)d_in[15];
  const float* W_uh = (const float*)d_in[16]; const float* b_uh = (const float*)d_in[17];
  const float* W_out= (const float*)d_in[18]; const float* b_out= (const float*)d_in[19];
  float* out = (float*)d_out;

  // ---- workspace: 3 rotating 67.1 MB buffers + weights (~201.6 MB) ----
  const size_t SLOT = (size_t)262144 * 128 * 2;
  const size_t need = 3 * SLOT + ((size_t)256 * 256 + 2 * (size_t)128 * 256) * 2 + 4096;
  fprintf(stderr, "[tree_lstm] ws_size=%zu need=%zu\n", ws_size, need);
  if (ws_size < need) {
    fprintf(stderr, "[tree_lstm] INSUFFICIENT WORKSPACE — skipping launch\n");
    return;
  }
  char* ws = (char*)d_ws;
  size_t off = 0;
  auto take = [&](size_t bytes) { char* p = ws + off; off += (bytes + 255) & ~(size_t)255; return p; };
  u16* X   = (u16*)take(SLOT);   // h_prev / h_cur (rotates with Y)
  u16* Bc  = (u16*)take(SLOT);   // c (prev consumed by k_fc before k_cell overwrites)
  u16* Y   = (u16*)take(SLOT);   // fcsum then h_cur (rotates with X)
  u16* Biu = (u16*)take((size_t)256 * 256 * 2);
  u16* Bo  = (u16*)take((size_t)128 * 256 * 2);
  u16* Bf  = (u16*)take((size_t)128 * 256 * 2);

  build_biu<<<256, 256, 0, stream>>>(W_ix, W_ih, W_ux, W_uh, Biu);
  build_bo<<<128, 256, 0, stream>>>(W_ox, W_oh, Bo);
  build_bf<<<128, 256, 0, stream>>>(W_fh, W_fx, Bf);

  const long LOFF[6] = {0, 4096, 20480, 86016, 217088, 479232};
  const int  LSZ[6]  = {4096, 16384, 65536, 131072, 262144, 262144};
  const int  LLR[5]  = {2, 2, 1, 1, 0};   // log2(children per node), L=0..4

  // ---- leaf level L=5: K=128, h_sum=0, no f-path. c->Bc, h->Y ----
  k_cell<1><<<LSZ[5] / 128, 256, 0, stream>>>(sen, emb, X, Biu, Bo,
      nullptr, Bc, Y, b_ix, b_ih, b_ux, b_uh, b_ox, b_oh, LOFF[5], 0, 0);
  { u16* t = X; X = Y; Y = t; }

  // ---- levels 4..0: k_fc (children) then fused k_cell (parents); swap ----
  for (int L = 4; L >= 0; L--) {
    const long o0 = LOFF[L];
    const int nL = LSZ[L], nC = LSZ[L + 1];
    const int lr = LLR[L], ratio = 1 << lr;
    k_fc<<<nC / 128, 256, 0, stream>>>(sen, emb, X, Bf, Bc, Y, b_fh, b_fx, o0, lr);
    k_cell<2><<<nL / 128, 256, 0, stream>>>(sen, emb, X, Biu, Bo,
        Y, Bc, Y, b_ix, b_ih, b_ux, b_uh, b_ox, b_oh, o0, ratio, 1);
    u16* t = X; X = Y; Y = t;
  }

  out_proj<<<64, 256, 0, stream>>>(X, W_out, b_out, out);
}